// Round 7
// baseline (43.222 us; speedup 1.0000x reference)
//
#include <hip/hip_runtime.h>
#include <hip/hip_bf16.h>
#include <math.h>

#define KL 64      // locations
#define NT 8192    // time steps
#define MF 8       // covariate features
#define DD 32      // memory depth
#define WIN 64     // 2*DD window taps
#define HD 20      // hidden dim
#define HP 32      // hidden padded to 2 MFMA N-tiles
#define KF 512     // 2*DD*MF = GEMM K
#define NB 256     // n-rows per block
#define NXB (NT / NB)          // 32 n-tiles
#define NBLK (NXB * KL)        // 2048 mlp blocks
#define NPART (NBLK * 4)       // 8192 per-wave partials
#define GRPS (KF / 8)          // 64 fragment groups (kk*4+g)
#define GROW 24                // rows/group: 20 real + zero rows (384B line-aligned)
#define W1SZ (GRPS * GROW * 8) // 12288 shorts = 24576 B (fits 32KB L1)

typedef __attribute__((ext_vector_type(8))) short bf16x8;
typedef __attribute__((ext_vector_type(4))) float f32x4;

// fast softplus: v_exp_f32 + v_log_f32
__device__ __forceinline__ float softplus_f(float x) {
    float e = __expf(-fabsf(x));
    return fmaxf(x, 0.0f) + __logf(1.0f + e);
}
__device__ __forceinline__ short f2bf(float x) {
    __hip_bfloat16 h = __float2bfloat16(x);
    return *reinterpret_cast<short*>(&h);
}

// ---- Kernel 1 (tiny): pack W1 -> fragment-ordered bf16, pad b1/W2 ----
// W1b[(grp*GROW + r)*8 + e] = W1[r][grp*8 + e]; r<HD real, r>=HD zero.
__global__ __launch_bounds__(256)
void pack_kernel(const float* __restrict__ W1, const float* __restrict__ b1,
                 const float* __restrict__ W2, short* __restrict__ W1b,
                 float* __restrict__ b1p, float* __restrict__ W2p) {
    int t = blockIdx.x * 256 + threadIdx.x;      // grid 16 -> 4096 threads
    #pragma unroll
    for (int i = 0; i < 3; ++i) {
        int p = t + i * 4096;                    // W1SZ = 12288
        int e = p & 7;
        int rg = p >> 3;
        int r = rg % GROW;
        int grp = rg / GROW;                     // 0..63 = kk*4 + g
        W1b[p] = (r < HD) ? f2bf(W1[r * KF + grp * 8 + e]) : (short)0;
    }
    if (blockIdx.x == 0 && threadIdx.x < HP) {
        b1p[threadIdx.x] = (threadIdx.x < HD) ? b1[threadIdx.x] : 0.0f;
        W2p[threadIdx.x] = (threadIdx.x < HD) ? W2[threadIdx.x] : 0.0f;
    }
}

// ---- Kernel 2: barrier-free wave-independent fused kernel ----
// Each wave owns rows [base, base+64), base = n0 + wave*64, with a PRIVATE LDS
// slice: its own 128-row cov window [base-32, base+96), its own 128-entry
// T slice [base-64, base+64), its own hsum. ZERO __syncthreads: no cross-wave
// LDS access; wave-internal ds ordering is compiler-enforced (lgkmcnt).
// T-dot interleaved into the MFMA loop; B-fragments from L1-resident W1b.
__global__ __launch_bounds__(256)
void mlp_mfma_kernel(const float* __restrict__ covs, const float* __restrict__ obs,
                     const float* __restrict__ halpha, const float* __restrict__ hbeta,
                     const short* __restrict__ W1b, const float* __restrict__ b1p,
                     const float* __restrict__ W2p, const float* __restrict__ b2,
                     const float* __restrict__ gamma, float* __restrict__ lams,
                     float* __restrict__ partial) {
    __shared__ short cov_s[4][128 * MF];   // per-wave [128 rows][8] bf16
    __shared__ float T_s[4][128];          // per-wave T slice [base-64, base+64)
    __shared__ float hsum[4][64];          // per-wave mu pre-activations

    int k    = blockIdx.y;
    int n0   = blockIdx.x * NB;
    int tid  = threadIdx.x;
    int lane = tid & 63;
    int wave = tid >> 6;
    int base = n0 + wave * 64;

    // hoisted scalars/loads: latency hides under staging + GEMM
    int n = base + lane;
    size_t idx = (size_t)k * NT + n;
    float obs_n = obs[idx];
    float beta  = hbeta[0];
    float gam   = gamma[k];
    float b2v   = b2[0];

    // ---- stage this wave's cov window (edge-clamped), 2 rows/lane ----
    const float* cbase = covs + (size_t)k * NT * MF;
    {
        int t1 = base - DD + lane;                 // [base-32, base+32); max 8159
        t1 = t1 < 0 ? 0 : t1;
        int t2 = base + DD + lane;                 // [base+32, base+96); min 32
        t2 = t2 > NT - 1 ? NT - 1 : t2;
        const float4* cp1 = (const float4*)(cbase + (size_t)t1 * MF);
        const float4* cp2 = (const float4*)(cbase + (size_t)t2 * MF);
        float4 a0 = cp1[0], a1 = cp1[1];
        float4 d0 = cp2[0], d1 = cp2[1];
        bf16x8 v1, v2;
        v1[0] = f2bf(a0.x); v1[1] = f2bf(a0.y); v1[2] = f2bf(a0.z); v1[3] = f2bf(a0.w);
        v1[4] = f2bf(a1.x); v1[5] = f2bf(a1.y); v1[6] = f2bf(a1.z); v1[7] = f2bf(a1.w);
        v2[0] = f2bf(d0.x); v2[1] = f2bf(d0.y); v2[2] = f2bf(d0.z); v2[3] = f2bf(d0.w);
        v2[4] = f2bf(d1.x); v2[5] = f2bf(d1.y); v2[6] = f2bf(d1.z); v2[7] = f2bf(d1.w);
        *(bf16x8*)&cov_s[wave][lane * MF] = v1;
        *(bf16x8*)&cov_s[wave][(lane + 64) * MF] = v2;
    }

    int c = lane & 15;
    int g = lane >> 4;

    f32x4 acc[4][2];
    #pragma unroll
    for (int mt = 0; mt < 4; ++mt) {
        acc[mt][0] = (f32x4){0.f, 0.f, 0.f, 0.f};
        acc[mt][1] = (f32x4){0.f, 0.f, 0.f, 0.f};
    }

    int r1 = (c < 4) ? (16 + c) : HD;              // c>=4 -> zero row 20
    const short* pB0 = W1b + g * (GROW * 8) + c * 8;
    const short* pB1 = W1b + g * (GROW * 8) + r1 * 8;
    const short* pA  = &cov_s[wave][(c + g) * MF];

    // T-dot state: T_s[wave][r] = dot(halpha[k,:], obs[:, base-64+r]), r=0..127
    const float* arow = halpha + (size_t)k * KL;   // wave-uniform -> s_load
    int tA = base - WIN + lane;
    tA = tA < 0 ? 0 : tA;                          // clamped entries guarded in FIR
    int tB = base + lane;                          // always in [0, NT)
    float aA = 0.0f, aB = 0.0f;

    #pragma unroll 2
    for (int kk = 0; kk < KF / 32; ++kk) {
        // 4 T j-steps interleaved under this kk's MFMA work
        #pragma unroll
        for (int jj = 0; jj < 4; ++jj) {
            int j = kk * 4 + jj;
            float ajv = arow[j];
            const float* orow = obs + (size_t)j * NT;
            aA = fmaf(ajv, orow[tA], aA);
            aB = fmaf(ajv, orow[tB], aB);
        }
        bf16x8 b0  = *(const bf16x8*)(pB0 + kk * (4 * GROW * 8));
        bf16x8 b1v = *(const bf16x8*)(pB1 + kk * (4 * GROW * 8));
        #pragma unroll
        for (int mt = 0; mt < 4; ++mt) {
            bf16x8 a = *(const bf16x8*)(pA + (mt * 16 + kk * 4) * MF);
            acc[mt][0] = __builtin_amdgcn_mfma_f32_16x16x32_bf16(a, b0,  acc[mt][0], 0, 0, 0);
            acc[mt][1] = __builtin_amdgcn_mfma_f32_16x16x32_bf16(a, b1v, acc[mt][1], 0, 0, 0);
        }
    }
    T_s[wave][lane] = aA;
    T_s[wave][64 + lane] = aB;

    // ---- epilogue: softplus + W2 dot, multi-value butterfly over 16 c-lanes ----
    // One shfl folds TWO values per level: 15 shfl total (vs 64 naive). Lane c
    // ends holding the full sum for value index bitrev4(c).
    float w2a = W2p[c],      b1a = b1p[c];
    float w2b = W2p[16 + c], b1b = b1p[16 + c];
    float cur[16];
    #pragma unroll
    for (int mt = 0; mt < 4; ++mt) {
        #pragma unroll
        for (int j = 0; j < 4; ++j) {
            cur[mt * 4 + j] = w2a * softplus_f(acc[mt][0][j] + b1a)
                            + w2b * softplus_f(acc[mt][1][j] + b1b);
        }
    }
    #pragma unroll
    for (int m = 1; m <= 8; m <<= 1) {
        int half = 8 / m;
        #pragma unroll
        for (int s = 0; s < half; ++s) {
            float x0 = cur[s], x1 = cur[s + half];
            float t = (lane & m) ? x0 : x1;
            float u = __shfl_xor(t, m, 64);
            cur[s] = ((lane & m) ? x1 : x0) + u;
        }
    }
    // value index held by this lane: iv = bitrev4(c); row_local = (iv>>2)*16 + g*4 + (iv&3)
    {
        int iv = ((c & 1) << 3) | ((c & 2) << 1) | ((c & 4) >> 1) | ((c & 8) >> 3);
        hsum[wave][(iv >> 2) * 16 + g * 4 + (iv & 3)] = cur[0];
    }

    // ---- lam1 via FIR on own T slice (4 interleaved chains), lam, loglik ----
    // Taps: tail after L <= T*beta*e^{-beta(L+1)}/(1-e^{-beta}), T<=0.64 ->
    // beta*L>=30 gives ~1e-13 error. L = 30/beta+2 (=17 at beta=2), capped at 64.
    float decay = __expf(-beta);
    int Lmax = (int)(30.0f / beta) + 2;
    if (Lmax > WIN) Lmax = WIN;
    float la = 0.0f;
    const float* Tp = &T_s[wave][64 + lane];
    if (n >= WIN) {                        // all taps valid (i <= Lmax <= 64 <= n)
        int it4 = (Lmax + 3) >> 2;
        float d2 = decay * decay;
        float d4 = d2 * d2;
        float w1 = beta * decay, w2 = w1 * decay, w3 = w2 * decay, w4 = w3 * decay;
        float la0 = 0.f, la1 = 0.f, la2 = 0.f, la3 = 0.f;
        for (int it = 0; it < it4; ++it) {
            int i = it * 4;
            la0 = fmaf(w1, Tp[-(i + 1)], la0); w1 *= d4;
            la1 = fmaf(w2, Tp[-(i + 2)], la1); w2 *= d4;
            la2 = fmaf(w3, Tp[-(i + 3)], la2); w3 *= d4;
            la3 = fmaf(w4, Tp[-(i + 4)], la3); w4 *= d4;
        }
        la = (la0 + la1) + (la2 + la3);
    } else {                               // only block 0 / wave 0 rows
        float w = beta * decay;
        for (int i = 1; i <= Lmax; ++i) {
            if (i <= n) la = fmaf(w, Tp[-i], la);
            w *= decay;
        }
    }
    float lam1 = softplus_f(la);
    float mu = softplus_f(hsum[wave][lane] + b2v);
    float lam = lam1 + gam * mu;
    lams[idx] = lam;
    float term = fmaf(obs_n, __logf(lam), -lam);

    #pragma unroll
    for (int off = 32; off > 0; off >>= 1) term += __shfl_down(term, off, 64);
    if (lane == 0)
        partial[((size_t)blockIdx.y * NXB + blockIdx.x) * 4 + wave] = term;
}

// ---- Kernel 3: sum 8192 per-wave partials -> out[0] ----
__global__ __launch_bounds__(256)
void finalize_kernel(const float* __restrict__ partial, float* __restrict__ out0) {
    __shared__ float wred[4];
    int tid = threadIdx.x;
    float s = 0.0f;
    #pragma unroll
    for (int i = 0; i < NPART / 256; ++i) s += partial[i * 256 + tid];
    #pragma unroll
    for (int off = 32; off > 0; off >>= 1) s += __shfl_down(s, off, 64);
    if ((tid & 63) == 0) wred[tid >> 6] = s;
    __syncthreads();
    if (tid == 0) out0[0] = (wred[0] + wred[1]) + (wred[2] + wred[3]);
}

extern "C" void kernel_launch(void* const* d_in, const int* in_sizes, int n_in,
                              void* d_out, int out_size, void* d_ws, size_t ws_size,
                              hipStream_t stream) {
    const float* obs    = (const float*)d_in[0];
    const float* covs   = (const float*)d_in[1];
    const float* hbeta  = (const float*)d_in[2];
    const float* halpha = (const float*)d_in[3];
    const float* gamma  = (const float*)d_in[4];
    const float* W1     = (const float*)d_in[5];
    const float* b1     = (const float*)d_in[6];
    const float* W2     = (const float*)d_in[7];
    const float* b2     = (const float*)d_in[8];

    float* out  = (float*)d_out;   // out[0]=loglik, out[1..]=lams [K][N]
    float* lams = out + 1;

    char* ws = (char*)d_ws;
    float* partial = (float*)ws;                 // 32 KB (8192 per-wave partials)
    float* b1p     = (float*)(ws + 32768);       // 128 B
    float* W2p     = (float*)(ws + 32896);       // 128 B
    short* W1b     = (short*)(ws + 33024);       // 24.5 KB, 16B aligned

    dim3 block(256);
    pack_kernel<<<dim3(16), block, 0, stream>>>(W1, b1, W2, W1b, b1p, W2p);
    mlp_mfma_kernel<<<dim3(NXB, KL), block, 0, stream>>>(
        covs, obs, halpha, hbeta, W1b, b1p, W2p, b2, gamma, lams, partial);
    finalize_kernel<<<1, block, 0, stream>>>(partial, out);
}